// Round 2
// baseline (8102.700 us; speedup 1.0000x reference)
//
#include <hip/hip_runtime.h>
#include <math.h>

// Batched exact Hungarian (Jonker-Volgenant shortest augmenting path),
// mirroring the JAX reference step-for-step so the argmin decisions (and
// hence the assignment) match exactly.
//
// B=32 batches, n=256, D=4. One wave (64 lanes) per batch; lane l owns
// columns j = l + 64k, k=0..3 (1-based jj = j+1). Column potentials v,
// minv, used, and the gt point live in registers; u, p, way, pred points
// live in LDS. Wave-synchronous: single wave per block, __syncthreads()
// only where a cross-lane LDS RAW hazard exists.
//
// Output dtype: harness reads d_out as FLOAT32 (round-1 evidence: int32
// stores read back as denormals ~0 -> absmax exactly 255). Store col4row
// as float-valued integers and total_cost as float.

#define NB   32
#define NN   256
#define ND   4
#define NPT  4      // columns per lane (256 / 64)
#define INFV 1e9f

__global__ __launch_bounds__(64) void hungarian_kernel(
    const float* __restrict__ pred, const float* __restrict__ gt,
    float* __restrict__ out)
{
#pragma clang fp contract(off)
    const int b    = blockIdx.x;
    const int lane = threadIdx.x;           // 0..63

    __shared__ float s_pred[NN][ND];        // pred points (broadcast reads)
    __shared__ float s_u[NN + 1];           // row potentials, 1-based
    __shared__ int   s_p[NN + 1];           // p[jj] = row matched to col jj (1-based), 0=free
    __shared__ int   s_way[NN + 1];         // predecessor column in Dijkstra tree

    // ---- load pred into LDS (coalesced float4), gt into registers ----
    const float* pb = pred + (size_t)b * NN * ND;
    const float* gb = gt   + (size_t)b * NN * ND;
    float gx[NPT], gy[NPT], gz[NPT], gw[NPT];
    for (int k = 0; k < NPT; ++k) {
        int idx = lane + 64 * k;
        float4 pv = ((const float4*)pb)[idx];
        s_pred[idx][0] = pv.x; s_pred[idx][1] = pv.y;
        s_pred[idx][2] = pv.z; s_pred[idx][3] = pv.w;
        float4 gv = ((const float4*)gb)[idx];
        gx[k] = gv.x; gy[k] = gv.y; gz[k] = gv.z; gw[k] = gv.w;
    }
    // ---- init potentials / matching ----
    for (int k = 0; k < NPT; ++k) {
        int jj = lane + 64 * k;
        s_u[jj] = 0.f; s_p[jj] = 0; s_way[jj] = 0;
    }
    if (lane == 0) { s_u[NN] = 0.f; s_p[NN] = 0; s_way[NN] = 0; }
    float v[NPT];
    for (int k = 0; k < NPT; ++k) v[k] = 0.f;
    __syncthreads();

    // ---- insert rows 1..n ----
    for (int i = 1; i <= NN; ++i) {
        if (lane == 0) s_p[0] = i;
        float minv[NPT]; bool used[NPT];
        for (int k = 0; k < NPT; ++k) { minv[k] = INFV; used[k] = false; }
        int j0 = 0;
        __syncthreads();   // p writes (augment of prev row / p[0]=i) -> reads below

        // ---- Dijkstra over columns ----
        for (int guard = 0; guard < NN + 2; ++guard) {
            const int i0   = s_p[j0];                 // broadcast read
            const float ui = s_u[i0];
            const float px = s_pred[i0 - 1][0], py = s_pred[i0 - 1][1];
            const float pz = s_pred[i0 - 1][2], pw = s_pred[i0 - 1][3];
            // mark used[j0] (owner lane) BEFORE scanning, like the reference
            if (j0 > 0 && ((j0 - 1) & 63) == lane) used[(j0 - 1) >> 6] = true;

            float best = INFV; int bestj = NN + 2;
            for (int k = 0; k < NPT; ++k) {
                const int jj = 1 + lane + 64 * k;
                float m;
                if (!used[k]) {
                    float dx = px - gx[k], dy = py - gy[k];
                    float dz = pz - gz[k], dw = pw - gw[k];
                    float ss = dx * dx + dy * dy + dz * dz + dw * dw;
                    float cur = sqrtf(ss) - ui - v[k];
                    if (cur < minv[k]) { minv[k] = cur; s_way[jj] = j0; }
                    m = minv[k];
                } else {
                    m = INFV;
                }
                if (m < best || (m == best && jj < bestj)) { best = m; bestj = jj; }
            }
            // wave argmin with lowest-index tie-break (matches jnp.argmin)
            for (int off = 32; off; off >>= 1) {
                float ov = __shfl_xor(best,  off);
                int   oj = __shfl_xor(bestj, off);
                if (ov < best || (ov == best && oj < bestj)) { best = ov; bestj = oj; }
            }
            const float delta = best;
            const int   j1    = bestj;
            // potentials update
            for (int k = 0; k < NPT; ++k) {
                if (used[k]) {
                    v[k] -= delta;
                    int r = s_p[1 + lane + 64 * k];   // distinct rows -> no conflict
                    s_u[r] += delta;
                } else {
                    minv[k] -= delta;
                }
            }
            if (lane == 0) s_u[i] += delta;           // virtual column 0 (p[0]=i)
            __syncthreads();                          // u writes -> next-iter reads
            j0 = j1;
            if (s_p[j0] == 0) break;                  // free column reached
        }

        // ---- augment along way[] (all lanes uniformly; same-value writes) ----
        while (j0 != 0) {
            int jprev = s_way[j0];
            s_p[j0] = s_p[jprev];
            j0 = jprev;
        }
    }
    __syncthreads();

    // ---- outputs (FLOAT32): col4row[b][r-1] = j ; total_cost[b] ----
    float tot = 0.f;
    for (int k = 0; k < NPT; ++k) {
        int j  = lane + 64 * k;      // 0-based column
        int r  = s_p[j + 1];         // 1-based matched row
        out[b * NN + (r - 1)] = (float)j;   // col4row as float
        float px = s_pred[r - 1][0], py = s_pred[r - 1][1];
        float pz = s_pred[r - 1][2], pw = s_pred[r - 1][3];
        float dx = px - gx[k], dy = py - gy[k];
        float dz = pz - gz[k], dw = pw - gw[k];
        tot += sqrtf(dx * dx + dy * dy + dz * dz + dw * dw);
    }
    for (int off = 32; off; off >>= 1) tot += __shfl_xor(tot, off);
    if (lane == 0) out[NB * NN + b] = tot;
}

extern "C" void kernel_launch(void* const* d_in, const int* in_sizes, int n_in,
                              void* d_out, int out_size, void* d_ws, size_t ws_size,
                              hipStream_t stream) {
    const float* pred = (const float*)d_in[0];
    const float* gt   = (const float*)d_in[1];
    float* out = (float*)d_out;
    hipLaunchKernelGGL(hungarian_kernel, dim3(NB), dim3(64), 0, stream,
                       pred, gt, out);
}

// Round 4
// 4344.837 us; speedup vs baseline: 1.8649x; 1.8649x over previous
//
#include <hip/hip_runtime.h>
#include <math.h>

// Batched exact Hungarian (Jonker-Volgenant), bit-exact replica of the JAX/
// numpy reference decisions. One wave per batch; lane l owns CONTIGUOUS
// columns j = 4l..4l+3 (1-based jj = 4l+k+1) so that "lowest jj" tie-break
// == "lowest k then lowest lane" == local-scan-order + ballot-lowest-lane.
//
// Latency-path design:
//  - value-only wave min via DPP (row_shr/row_bcast) + ballot + readlane
//  - p[] mirrored in registers (pl[k]); i0_next via readlane from owner
//  - u[i0_next]/pred[i0_next] prefetched as soon as j1 known (provably
//    unmodified this run: j1 was unused => its row's u untouched)
//  - u of used columns accumulated in owner registers (same per-element
//    rounding sequence as reference), written back once per row
//  - no per-iteration __syncthreads (single wave, in-order LDS pipe);
//    2 barriers per row cover way-writes->augment and u-writeback->next-row
//
// Output dtype: harness reads d_out as float32; col4row stored as floats.

#define NB   32
#define NN   256
#define ND   4
#define NPT  4
#define INFV 1e9f

__device__ __forceinline__ float wave_min_bcast(float x) {
    // full 64-lane min; returns broadcast value (via readlane 63)
    int inf = __float_as_int(INFV);
    int t;
    t = __builtin_amdgcn_update_dpp(inf, __float_as_int(x), 0x111, 0xF, 0xF, false); // row_shr:1
    x = fminf(x, __int_as_float(t));
    t = __builtin_amdgcn_update_dpp(inf, __float_as_int(x), 0x112, 0xF, 0xF, false); // row_shr:2
    x = fminf(x, __int_as_float(t));
    t = __builtin_amdgcn_update_dpp(inf, __float_as_int(x), 0x114, 0xF, 0xF, false); // row_shr:4
    x = fminf(x, __int_as_float(t));
    t = __builtin_amdgcn_update_dpp(inf, __float_as_int(x), 0x118, 0xF, 0xF, false); // row_shr:8
    x = fminf(x, __int_as_float(t));
    t = __builtin_amdgcn_update_dpp(inf, __float_as_int(x), 0x142, 0xF, 0xF, false); // row_bcast:15
    x = fminf(x, __int_as_float(t));
    t = __builtin_amdgcn_update_dpp(inf, __float_as_int(x), 0x143, 0xF, 0xF, false); // row_bcast:31
    x = fminf(x, __int_as_float(t));
    return __int_as_float(__builtin_amdgcn_readlane(__float_as_int(x), 63));
}

__global__ __launch_bounds__(64) void hungarian_kernel(
    const float* __restrict__ pred, const float* __restrict__ gt,
    float* __restrict__ out)
{
#pragma clang fp contract(off)
    const int b    = blockIdx.x;
    const int lane = threadIdx.x;

    __shared__ float s_pred[NN][ND];   // pred points, 16B rows
    __shared__ float s_u[NN + 1];      // row potentials (1-based)
    __shared__ int   s_p[NN + 1];      // p[jj] = matched row (1-based)
    __shared__ int   s_way[NN];        // way, swizzled: [(jm1&3)*64 + (jm1>>2)]

    const float* pb = pred + (size_t)b * NN * ND;
    const float* gb = gt   + (size_t)b * NN * ND;

    // stage pred -> LDS (coalesced float4)
    #pragma unroll
    for (int k = 0; k < NPT; ++k) {
        int idx = lane + 64 * k;
        float4 pv = ((const float4*)pb)[idx];
        *(float4*)&s_pred[idx][0] = pv;
    }
    // gt points for owned columns 4*lane+k
    float gx[NPT], gy[NPT], gz[NPT], gw[NPT];
    #pragma unroll
    for (int k = 0; k < NPT; ++k) {
        float4 gv = ((const float4*)gb)[4 * lane + k];
        gx[k] = gv.x; gy[k] = gv.y; gz[k] = gv.z; gw[k] = gv.w;
    }
    #pragma unroll
    for (int k = 0; k < NPT; ++k) {
        int jj = lane + 64 * k;
        s_u[jj] = 0.f; s_p[jj] = 0;
    }
    if (lane == 0) { s_u[NN] = 0.f; s_p[NN] = 0; }
    float v[NPT]; int pl[NPT];
    #pragma unroll
    for (int k = 0; k < NPT; ++k) { v[k] = 0.f; pl[k] = 0; }
    __syncthreads();

    for (int i = 1; i <= NN; ++i) {
        if (lane == 0) s_p[0] = i;
        float minv[NPT], uacc[NPT]; bool used[NPT];
        #pragma unroll
        for (int k = 0; k < NPT; ++k) { minv[k] = INFV; used[k] = false; uacc[k] = 0.f; }
        float u_i = 0.f;                              // accumulates u[i]
        int   j1  = 0;                                // current j0
        float ui  = 0.f;                              // u[p[j0]]; u[i]==0 at row start
        float4 pr = *(const float4*)&s_pred[i - 1][0];

        for (int it = 0; it < NN + 2; ++it) {
            // mark used[j1] (owner lane), snapshot its u (= broadcast ui)
            if (j1 > 0) {
                int jm1 = j1 - 1;
                bool own = (jm1 >> 2) == lane;
                int  kk  = jm1 & 3;
                #pragma unroll
                for (int k = 0; k < NPT; ++k) {
                    bool hit = own && (kk == k);
                    used[k] = used[k] || hit;
                    uacc[k] = hit ? ui : uacc[k];
                }
            }
            // scan owned columns (bit-exact vs reference per column)
            float best = INFV; int bestk = 0;
            #pragma unroll
            for (int k = 0; k < NPT; ++k) {
                if (!used[k]) {
                    float dx = pr.x - gx[k], dy = pr.y - gy[k];
                    float dz = pr.z - gz[k], dw = pr.w - gw[k];
                    float ss = dx * dx + dy * dy + dz * dz + dw * dw;
                    float cur = sqrtf(ss) - ui - v[k];
                    if (cur < minv[k]) { minv[k] = cur; s_way[(k << 6) + lane] = j1; }
                    if (minv[k] < best) { best = minv[k]; bestk = k; }
                }
            }
            // wave argmin: value min via DPP, owner via ballot (lowest lane
            // == lowest jj, matching jnp.argmin first-occurrence)
            const float gmin = wave_min_bcast(best);
            unsigned long long msk = __ballot(best == gmin);
            int owner = __ffsll(msk) - 1;
            int psel = pl[0];
            psel = (bestk == 1) ? pl[1] : psel;
            psel = (bestk == 2) ? pl[2] : psel;
            psel = (bestk == 3) ? pl[3] : psel;
            int code_local = (4 * lane + bestk + 1) | (psel << 12);
            int code = __builtin_amdgcn_readlane(code_local, owner);
            int j1n  = code & 0xFFF;
            int i0n  = code >> 12;
            // prefetch next iteration's u and pred row (not modified this run)
            int pidx = (i0n > 0) ? (i0n - 1) : 0;
            float  ui_n = s_u[i0n];
            float4 pr_n = *(const float4*)&s_pred[pidx][0];
            // potential updates (delta = gmin), same rounding as reference
            const float delta = gmin;
            #pragma unroll
            for (int k = 0; k < NPT; ++k) {
                if (used[k]) { v[k] -= delta; uacc[k] += delta; }
                else         { minv[k] -= delta; }
            }
            u_i += delta;
            j1 = j1n;
            if (i0n == 0) break;     // free column found (updates already done)
            ui = ui_n; pr = pr_n;
        }

        __syncthreads();   // way writes (scan) visible before augment reads
        // write back u for used columns + current row
        #pragma unroll
        for (int k = 0; k < NPT; ++k)
            if (used[k]) s_u[pl[k]] = uacc[k];
        if (lane == 0) s_u[i] = u_i;
        // augment along way chain (uniform walk; owners update pl)
        int j = j1;
        while (j != 0) {
            int jm1 = j - 1;
            int jp  = s_way[((jm1 & 3) << 6) + (jm1 >> 2)];
            int val = s_p[jp];
            if (lane == 0) s_p[j] = val;
            bool own = (jm1 >> 2) == lane;
            int  kk  = jm1 & 3;
            #pragma unroll
            for (int k = 0; k < NPT; ++k)
                pl[k] = (own && kk == k) ? val : pl[k];
            j = jp;
        }
        __syncthreads();   // u/p writes visible before next row
    }

    // outputs (float32): col4row[b][r-1] = j ; total_cost[b]
    float tot = 0.f;
    #pragma unroll
    for (int k = 0; k < NPT; ++k) {
        int j = 4 * lane + k;
        int r = pl[k];                        // 1-based matched row
        out[b * NN + (r - 1)] = (float)j;
        float4 p4 = *(const float4*)&s_pred[r - 1][0];
        float dx = p4.x - gx[k], dy = p4.y - gy[k];
        float dz = p4.z - gz[k], dw = p4.w - gw[k];
        tot += sqrtf(dx * dx + dy * dy + dz * dz + dw * dw);
    }
    for (int off = 32; off; off >>= 1) tot += __shfl_xor(tot, off);
    if (lane == 0) out[NB * NN + b] = tot;
}

extern "C" void kernel_launch(void* const* d_in, const int* in_sizes, int n_in,
                              void* d_out, int out_size, void* d_ws, size_t ws_size,
                              hipStream_t stream) {
    const float* pred = (const float*)d_in[0];
    const float* gt   = (const float*)d_in[1];
    float* out = (float*)d_out;
    hipLaunchKernelGGL(hungarian_kernel, dim3(NB), dim3(64), 0, stream,
                       pred, gt, out);
}

// Round 5
// 3040.986 us; speedup vs baseline: 2.6645x; 1.4288x over previous
//
#include <hip/hip_runtime.h>
#include <math.h>

// Batched exact Hungarian (Jonker-Volgenant), bit-exact replica of the JAX/
// numpy reference decisions. One wave per batch; lane l owns CONTIGUOUS
// columns j = 4l..4l+3 (1-based jj = 4l+k+1): "lowest jj" tie-break ==
// lowest-k-locally then lowest-lane (ballot+ffs) == jnp.argmin first-occur.
//
// Round-5 latency surgery (vs round-4's 4345us / ~320cy per Dijkstra iter):
//  - speculative per-lane prefetch: after the local scan each lane ds_reads
//    u/pred of ITS OWN candidate row (psel); the DPP reduce + ballot +
//    potential updates cover the ~120cy LDS latency; winner's values pulled
//    via 5 v_readlane (owner lane is wave-uniform). Removes the dependent
//    ds_read from the critical path.
//  - way[] lives in registers (cndmask), flushed to LDS once per row-run
//    (kills the per-iteration conditional ds_write + exec juggling).
//  - branchless scan/updates: usedf in {0,+inf} folded additively (x+0.0f
//    exact; +inf gates like reference's where-INF since all genuine values
//    < 1e9), used01 in {0,1}: du = delta*used01 (delta*1=delta, v-0=v,
//    minv-(delta-delta)=minv -- all exact, reference value sequence kept).
//
// Output dtype: harness reads d_out as float32; col4row stored as floats.

#define NB   32
#define NN   256
#define ND   4
#define NPT  4
#define INFV 1e9f

__device__ __forceinline__ float wave_min_bcast(float x) {
    // full 64-lane min; returns broadcast value (via readlane 63).
    // Fill value 1e9 never corrupts the min (all genuine candidates < 1e9).
    int inf = __float_as_int(INFV);
    int t;
    t = __builtin_amdgcn_update_dpp(inf, __float_as_int(x), 0x111, 0xF, 0xF, false); // row_shr:1
    x = fminf(x, __int_as_float(t));
    t = __builtin_amdgcn_update_dpp(inf, __float_as_int(x), 0x112, 0xF, 0xF, false); // row_shr:2
    x = fminf(x, __int_as_float(t));
    t = __builtin_amdgcn_update_dpp(inf, __float_as_int(x), 0x114, 0xF, 0xF, false); // row_shr:4
    x = fminf(x, __int_as_float(t));
    t = __builtin_amdgcn_update_dpp(inf, __float_as_int(x), 0x118, 0xF, 0xF, false); // row_shr:8
    x = fminf(x, __int_as_float(t));
    t = __builtin_amdgcn_update_dpp(inf, __float_as_int(x), 0x142, 0xF, 0xF, false); // row_bcast:15
    x = fminf(x, __int_as_float(t));
    t = __builtin_amdgcn_update_dpp(inf, __float_as_int(x), 0x143, 0xF, 0xF, false); // row_bcast:31
    x = fminf(x, __int_as_float(t));
    return __int_as_float(__builtin_amdgcn_readlane(__float_as_int(x), 63));
}

__device__ __forceinline__ float readlane_f(float v, int lane) {
    return __int_as_float(__builtin_amdgcn_readlane(__float_as_int(v), lane));
}

__global__ __launch_bounds__(64) void hungarian_kernel(
    const float* __restrict__ pred, const float* __restrict__ gt,
    float* __restrict__ out)
{
#pragma clang fp contract(off)
    const int b    = blockIdx.x;
    const int lane = threadIdx.x;

    __shared__ float s_pred[NN][ND];   // pred points, 16B rows
    __shared__ float s_u[NN + 1];      // row potentials (1-based)
    __shared__ int   s_p[NN + 1];      // p[jj] = matched row (1-based)
    __shared__ int   s_way[NN];        // way, swizzled: [k*64 + lane] for jj-1 = 4*lane+k

    const float* pb = pred + (size_t)b * NN * ND;
    const float* gb = gt   + (size_t)b * NN * ND;

    #pragma unroll
    for (int k = 0; k < NPT; ++k) {
        int idx = lane + 64 * k;
        float4 pv = ((const float4*)pb)[idx];
        *(float4*)&s_pred[idx][0] = pv;
    }
    float gx[NPT], gy[NPT], gz[NPT], gw[NPT];
    #pragma unroll
    for (int k = 0; k < NPT; ++k) {
        float4 gv = ((const float4*)gb)[4 * lane + k];
        gx[k] = gv.x; gy[k] = gv.y; gz[k] = gv.z; gw[k] = gv.w;
    }
    #pragma unroll
    for (int k = 0; k < NPT; ++k) {
        int jj = lane + 64 * k;
        s_u[jj] = 0.f; s_p[jj] = 0;
    }
    if (lane == 0) { s_u[NN] = 0.f; s_p[NN] = 0; }
    float v[NPT]; int pl[NPT];
    #pragma unroll
    for (int k = 0; k < NPT; ++k) { v[k] = 0.f; pl[k] = 0; }
    const float FINF = __int_as_float(0x7f800000);
    __syncthreads();

    for (int i = 1; i <= NN; ++i) {
        if (lane == 0) s_p[0] = i;     // visible to augment via post-loop barrier
        float minv[NPT], uacc[NPT], usedf[NPT], used01[NPT];
        int   wayr[NPT];
        #pragma unroll
        for (int k = 0; k < NPT; ++k) {
            minv[k] = INFV; uacc[k] = 0.f; usedf[k] = 0.f; used01[k] = 0.f; wayr[k] = 0;
        }
        float u_i = 0.f;
        int   j1  = 0;
        float ui  = 0.f;                          // u[i]=0 at row start
        float4 pr = *(const float4*)&s_pred[i - 1][0];
        int   i0n = i;

        for (int it = 0; it < NN + 2; ++it) {
            // mark column j1 as used (owner lane), snapshot its row's u (= ui)
            if (j1 > 0) {
                int jm1 = j1 - 1;                 // wave-uniform scalar
                #pragma unroll
                for (int k = 0; k < NPT; ++k) {
                    bool hit = (4 * lane + k) == jm1;
                    usedf[k]  = hit ? FINF : usedf[k];
                    used01[k] = hit ? 1.0f : used01[k];
                    uacc[k]   = hit ? ui   : uacc[k];
                }
            }
            // branchless scan (per-column arithmetic == reference exactly)
            float m[NPT];
            #pragma unroll
            for (int k = 0; k < NPT; ++k) {
                float dx = pr.x - gx[k], dy = pr.y - gy[k];
                float dz = pr.z - gz[k], dw = pr.w - gw[k];
                float ss = dx * dx + dy * dy + dz * dz + dw * dw;
                float cur = ((sqrtf(ss) - ui) - v[k]) + usedf[k];   // +0 exact / +inf gates
                float old = minv[k];
                minv[k] = fminf(old, cur);
                wayr[k] = (cur < old) ? j1 : wayr[k];
                m[k] = minv[k] + usedf[k];        // argmin mask (inf for used)
            }
            // local argmin, first-occurrence (strict <, ascending k)
            float best = m[0]; int bestk = 0;
            if (m[1] < best) { best = m[1]; bestk = 1; }
            if (m[2] < best) { best = m[2]; bestk = 2; }
            if (m[3] < best) { best = m[3]; bestk = 3; }
            int psel = pl[0];
            psel = (bestk == 1) ? pl[1] : psel;
            psel = (bestk == 2) ? pl[2] : psel;
            psel = (bestk == 3) ? pl[3] : psel;
            // speculative prefetch of candidate row's u/pred (covered by the
            // reduce + updates below; consumed via readlane after winner known)
            int pidx = (psel > 0) ? (psel - 1) : 0;
            float  u_spec = s_u[psel];
            float4 p_spec = *(const float4*)&s_pred[pidx][0];
            int code_local = (4 * lane + bestk + 1) | (psel << 12);
            // wave argmin: value min via DPP; owner = lowest lane at min
            const float gmin = wave_min_bcast(best);
            unsigned long long msk = __ballot(best == gmin);
            int owner = __ffsll(msk) - 1;
            int code  = __builtin_amdgcn_readlane(code_local, owner);
            int j1n   = code & 0xFFF;
            i0n       = code >> 12;
            // potential updates (delta = gmin), reference value sequence
            const float delta = gmin;
            #pragma unroll
            for (int k = 0; k < NPT; ++k) {
                float du = delta * used01[k];     // delta if used, +-0 else
                v[k]    -= du;
                minv[k] -= (delta - du);          // -delta if unused, -0 else
                uacc[k] += du;
            }
            u_i += delta;
            j1 = j1n;
            if (i0n == 0) break;                  // free column (updates done)
            ui   = readlane_f(u_spec, owner);
            pr.x = readlane_f(p_spec.x, owner);
            pr.y = readlane_f(p_spec.y, owner);
            pr.z = readlane_f(p_spec.z, owner);
            pr.w = readlane_f(p_spec.w, owner);
        }

        // flush way registers to LDS (stride-1 per k, conflict-free)
        #pragma unroll
        for (int k = 0; k < NPT; ++k) s_way[(k << 6) + lane] = wayr[k];
        __syncthreads();   // way/p0 writes visible before augment reads
        // write back u for used columns + current row (pl still pre-augment)
        #pragma unroll
        for (int k = 0; k < NPT; ++k)
            if (used01[k] != 0.0f) s_u[pl[k]] = uacc[k];
        if (lane == 0) s_u[i] = u_i;
        // augment along way chain (uniform walk; owners update pl)
        int j = j1;
        while (j != 0) {
            int jm1 = j - 1;
            int jp  = s_way[((jm1 & 3) << 6) + (jm1 >> 2)];
            int val = s_p[jp];
            if (lane == 0) s_p[j] = val;
            bool own = (jm1 >> 2) == lane;
            int  kk  = jm1 & 3;
            #pragma unroll
            for (int k = 0; k < NPT; ++k)
                pl[k] = (own && kk == k) ? val : pl[k];
            j = jp;
        }
        __syncthreads();   // u/p writes visible before next row's spec reads
    }

    // outputs (float32): col4row[b][r-1] = j ; total_cost[b]
    float tot = 0.f;
    #pragma unroll
    for (int k = 0; k < NPT; ++k) {
        int j = 4 * lane + k;
        int r = pl[k];                        // 1-based matched row
        out[b * NN + (r - 1)] = (float)j;
        float4 p4 = *(const float4*)&s_pred[r - 1][0];
        float dx = p4.x - gx[k], dy = p4.y - gy[k];
        float dz = p4.z - gz[k], dw = p4.w - gw[k];
        tot += sqrtf(dx * dx + dy * dy + dz * dz + dw * dw);
    }
    for (int off = 32; off; off >>= 1) tot += __shfl_xor(tot, off);
    if (lane == 0) out[NB * NN + b] = tot;
}

extern "C" void kernel_launch(void* const* d_in, const int* in_sizes, int n_in,
                              void* d_out, int out_size, void* d_ws, size_t ws_size,
                              hipStream_t stream) {
    const float* pred = (const float*)d_in[0];
    const float* gt   = (const float*)d_in[1];
    float* out = (float*)d_out;
    hipLaunchKernelGGL(hungarian_kernel, dim3(NB), dim3(64), 0, stream,
                       pred, gt, out);
}